// Round 16
// baseline (95.010 us; speedup 1.0000x reference)
//
#include <hip/hip_runtime.h>

// Fused SNN forward for MI355X (gfx950) — round 16.
// r15 evidence: occupancy 27->45% with FLAT duration => limiter is a shared
// per-CU pipe, and the DS ledger says it's LDS: ~790 DS instrs/block (~40us
// of per-CU DS time), half of it phase-1's scattered count stores.
// Fix via layout coincidence: in the A-frag layout the 8 contiguous shorts
// at fixed (ks,s,t) are 8 CONSECUTIVE units. Re-partition: thread T owns
// units 8T..8T+7 (1352 = 169*8 -> T<169 all-valid; T=169..171 zero-pad).
// Per timestep each thread emits ONE aligned ds_write_b128 (8 bf16 counts
// packed with 4 v_perm): phase-1 DS 384 -> 48 instrs/block, conflict-free.
// sA back to bf16 (r14): no phase-2 unpack. Phase 2 / 4-way exact bf16
// weight split / combine / LIF-2 identical to r14 (absmax 0 validated).

typedef float v2f __attribute__((ext_vector_type(2)));
typedef float f32x4 __attribute__((ext_vector_type(4)));
typedef short s16x8 __attribute__((ext_vector_type(8)));

#if __has_builtin(__builtin_elementwise_fma)
#define VFMA(a, b, c) __builtin_elementwise_fma((a), (b), (c))
#else
#define VFMA(a, b, c) ((a) * (b) + (c))
#endif

#define NU 8        // units per thread: 8 consecutive = one A-frag jj-run
#define KS 43       // K-blocks of 32: 43*32 = 1376 >= 1352
#define SPLITS 4    // exact bf16 decomposition of fp32 weights (== waves)

__device__ __forceinline__ unsigned short bf16_rne(float f) {
    unsigned u = __float_as_uint(f);
    return (unsigned short)((u + 0x7FFFu + ((u >> 16) & 1u)) >> 16);
}
__device__ __forceinline__ float bf16_back(unsigned short h) {
    return __uint_as_float(((unsigned)h) << 16);
}

// pack two small-int floats into one bf16-pair word (exact): lo | hi<<16
__device__ __forceinline__ unsigned bf16pair(float flo, float fhi) {
#if __has_builtin(__builtin_amdgcn_perm)
    return __builtin_amdgcn_perm(__float_as_uint(fhi), __float_as_uint(flo),
                                 0x07060302u);
#else
    return (__float_as_uint(fhi) & 0xFFFF0000u) | (__float_as_uint(flo) >> 16);
#endif
}

// ---- pre-kernel: build B fragments (4-way exact bf16 split of 0.25*fc_w)
__global__ void build_bfrag_kernel(const float* __restrict__ fc_w,
                                   s16x8* __restrict__ wsfrag) {
    const int blk = blockIdx.x;          // p*KS + ks
    const int p   = blk / KS;
    const int ks  = blk - p * KS;
    const int l   = threadIdx.x;         // 0..63
    s16x8 frag;
    #pragma unroll
    for (int jj = 0; jj < 8; ++jj) {
        const int k = ks * 32 + (l >> 4) * 8 + jj;
        const int n = l & 15;
        float r = (k < 1352 && n < 10) ? 0.25f * fc_w[n * 1352 + k] : 0.0f;
        unsigned short b = 0;
        for (int q = 0; q <= p; ++q) {   // p-th split term
            b = bf16_rne(r);
            r -= bf16_back(b);
        }
        frag[jj] = (short)b;
    }
    wsfrag[blk * 64 + l] = frag;
}

__global__ __launch_bounds__(256, 3) void snn_fused_kernel(
    const float* __restrict__ x,        // [4096, 1, 28, 28]
    const float* __restrict__ conv_w,   // [8, 1, 3, 3]
    const s16x8* __restrict__ wsfrag,   // [SPLITS*KS*64] B fragments
    float* __restrict__ out)            // [4096, 10]
{
    const int b    = blockIdx.x;
    const int tid  = threadIdx.x;
    const int lane = tid & 63;
    const int wid  = tid >> 6;          // 0..3

    // bf16 counts matrix in A-fragment order:
    // short index(u,t) = (u>>5)*544 + ((u&31)>>3)*136 + t*8 + (u&7)
    // thread T owns u = 8T..8T+7 -> base short = (T>>2)*544 + (T&3)*136,
    // per-t write = 8 shorts at +t*8 (16B-aligned -> ds_write_b128).
    __shared__ __align__(16) unsigned short sA[KS * 544];  // 46.75 KB
    __shared__ float scC[4 * 256];            // per-wave partial C [w][t*16+o]
    __shared__ float scw[72];                 // conv weights
    __shared__ float scur2[160];              // [t][o]

    if (tid < 72) scw[tid] = conv_w[tid];

    v2f cur2[NU][2];   // conv out [unit][{cells01, cells23}]
    v2f mem2[NU][2];   // LIF-1 membranes
    int sbyte = (tid >> 2) * 1088 + (tid & 3) * 272;   // byte base in sA

    // ---- per-thread geometry (units all valid for tid < 169) ----
    int xbase[NU], kbase[NU];
    if (tid < 169) {
        #pragma unroll
        for (int i = 0; i < NU; ++i) {
            const int u   = tid * 8 + i;
            const int k   = u / 169;          // channel
            const int rem = u - k * 169;
            const int pr  = rem / 13;         // pool row
            const int pc  = rem - pr * 13;    // pool col
            xbase[i] = 56 * pr + 2 * pc;
            kbase[i] = 9 * k;
        }
    }
    __syncthreads();                          // scw ready

    if (tid < 169) {
        // ---- conv straight from global (3KB image, L2/L3-resident) ----
        const float* xb = x + (size_t)b * 784;
        #pragma unroll
        for (int i = 0; i < NU; ++i) {
            float cw[9];
            #pragma unroll
            for (int qq = 0; qq < 9; ++qq) cw[qq] = scw[kbase[i] + qq];

            float xr[4][4];
            #pragma unroll
            for (int r = 0; r < 4; ++r) {
                const float2* rp = reinterpret_cast<const float2*>(xb + xbase[i] + 28 * r);
                const float2 a = rp[0], c2 = rp[1];
                xr[r][0] = a.x; xr[r][1] = a.y; xr[r][2] = c2.x; xr[r][3] = c2.y;
            }

            float cell[2][2];
            #pragma unroll
            for (int dr = 0; dr < 2; ++dr)
                #pragma unroll
                for (int dc = 0; dc < 2; ++dc) {
                    float acc = 0.0f;
                    #pragma unroll
                    for (int ki = 0; ki < 3; ++ki)
                        #pragma unroll
                        for (int kj = 0; kj < 3; ++kj)
                            acc += xr[dr + ki][dc + kj] * cw[ki * 3 + kj];
                    cell[dr][dc] = acc;
                }
            cur2[i][0] = (v2f){cell[0][0], cell[0][1]};
            cur2[i][1] = (v2f){cell[1][0], cell[1][1]};
            mem2[i][0] = (v2f){0.0f, 0.0f};
            mem2[i][1] = (v2f){0.0f, 0.0f};
        }

        // ---- phase 1: 16 timesteps of pure LIF; 1 b128 store per t ----
        const v2f half2 = (v2f){0.5f, 0.5f};
        #pragma unroll
        for (int t = 0; t < 16; ++t) {
            float c[NU];
            #pragma unroll
            for (int i = 0; i < NU; ++i) {
                v2f m01 = VFMA(half2, mem2[i][0], cur2[i][0]);
                v2f m23 = VFMA(half2, mem2[i][1], cur2[i][1]);
                v2f sp01, sp23;
                sp01.x = m01.x > 1.0f ? 1.0f : 0.0f;   // spike iff m > THR
                sp01.y = m01.y > 1.0f ? 1.0f : 0.0f;
                sp23.x = m23.x > 1.0f ? 1.0f : 0.0f;
                sp23.y = m23.y > 1.0f ? 1.0f : 0.0f;
                mem2[i][0] = m01 - sp01;               // subtract-reset (bit-identical)
                mem2[i][1] = m23 - sp23;
                v2f s = sp01 + sp23;
                c[i] = s.x + s.y;                      // 0..4 exact
            }
            uint4 w;
            w.x = bf16pair(c[0], c[1]);
            w.y = bf16pair(c[2], c[3]);
            w.z = bf16pair(c[4], c[5]);
            w.w = bf16pair(c[6], c[7]);
            *reinterpret_cast<uint4*>(
                reinterpret_cast<char*>(sA) + sbyte + t * 16) = w;
        }
    } else if (tid < 172) {
        // zero-pad rows for units 1352..1375
        const uint4 z = (uint4){0u, 0u, 0u, 0u};
        #pragma unroll
        for (int t = 0; t < 16; ++t)
            *reinterpret_cast<uint4*>(
                reinterpret_cast<char*>(sA) + sbyte + t * 16) = z;
    }
    __syncthreads();                                   // counts complete

    // ---- phase 2: wave p computes split p of the [16x1376]x[1376x16] ----
    {
        const int p = wid;                             // split index == wave id
        f32x4 acc = (f32x4){0.f, 0.f, 0.f, 0.f};
        const int arow = (lane >> 4) * 136 + (lane & 15) * 8;
        #pragma unroll 2
        for (int ks = 0; ks < KS; ++ks) {
            const s16x8 a  = *reinterpret_cast<const s16x8*>(&sA[ks * 544 + arow]);
            const s16x8 bw = wsfrag[(p * KS + ks) * 64 + lane];
            acc = __builtin_amdgcn_mfma_f32_16x16x32_bf16(a, bw, acc, 0, 0, 0);
        }
        // store partial C: row t = (l>>4)*4 + r, col o = l&15 (verified layout)
        const int o = lane & 15;
        #pragma unroll
        for (int r = 0; r < 4; ++r) {
            const int t = (lane >> 4) * 4 + r;
            scC[wid * 256 + t * 16 + o] = acc[r];
        }
    }
    __syncthreads();                                   // partials ready

    // ---- combine splits (same pairwise order as r13/r14) + LIF-2 scan ----
    if (tid < 160) {
        const int t = tid / 10;
        const int o = tid - t * 10;
        const int idx = t * 16 + o;
        scur2[tid] = (scC[idx] + scC[256 + idx]) + (scC[512 + idx] + scC[768 + idx]);
    }
    __syncthreads();                                   // scur2 ready

    if (tid < 10) {
        float m2 = 0.0f, cnt = 0.0f;
        #pragma unroll
        for (int t = 0; t < 16; ++t) {
            m2 = __builtin_fmaf(0.5f, m2, scur2[t * 10 + tid]);
            float ms = m2 - 1.0f;
            bool  sp = ms > 0.0f;
            m2  = sp ? ms : m2;
            cnt += sp ? 1.0f : 0.0f;
        }
        out[(size_t)b * 10 + tid] = cnt;
    }
}

extern "C" void kernel_launch(void* const* d_in, const int* in_sizes, int n_in,
                              void* d_out, int out_size, void* d_ws, size_t ws_size,
                              hipStream_t stream) {
    const float* x      = (const float*)d_in[0];  // 4096*784
    const float* conv_w = (const float*)d_in[1];  // 72
    const float* fc_w   = (const float*)d_in[2];  // 13520
    float* out          = (float*)d_out;          // 40960
    s16x8* wsfrag       = (s16x8*)d_ws;           // needs 176128 B

    build_bfrag_kernel<<<SPLITS * KS, 64, 0, stream>>>(fc_w, wsfrag);

    const int B = in_sizes[0] / 784;              // 4096
    snn_fused_kernel<<<B, 256, 0, stream>>>(x, conv_w, wsfrag, out);
}